// Round 12
// baseline (169.416 us; speedup 1.0000x reference)
//
#include <hip/hip_runtime.h>

#define N_NODES   50000
#define N_EDGES   800000
#define IN_DIM    100
#define HIDDEN    16
#define N_CLASSES 40

// Bucketing geometry: bucket = dst >> 6 (64 nodes per bucket)
#define BSHIFT 6
#define NPB    64                        // nodes per bucket
#define NBKT   782                       // ceil(N_NODES / NPB)
#define PB     256                       // partition blocks/regions
#define EPB    3125                      // edges per region (256*3125 = 800000)
#define EPT    7                         // max edges in regs/thread (ceil(3125/512))
#define GEMMB  782                       // gemm tiles of 64 rows

// Fixed-point scales for the LDS int accumulators.
// Layer 1: |z1| < 8192 guaranteed (real ~100, 6-sigma ~75)  -> 2^18
// Layer 2: |z2| < 32768 guaranteed (real ~200, 19-sigma)    -> 2^16
#define SCALE1 262144.0f
#define INV1   3.814697265625e-06f
#define SCALE2 65536.0f
#define INV2   1.52587890625e-05f

// K1 LDS union:
//  partition: cnt[782]@0(3200) | lcur@3200(3200) | wpre[8]@6400
//             | staged int2[3125]@8448 .. 33448
//  gemm:      sX[64*100]@0 .. 25600 | sW[1600]@25600 .. 32000
#define K1_LDS 33456

// ---------------------------------------------------------------------------
// K1: blocks [0,PB) partition the edge list (edges held in REGISTERS between
// count and scatter -> single global read); blocks [PB, PB+GEMMB) compute
// y1 = X @ W1 concurrently. Verified rounds 7/10/11.
// BTt transposed: BTt[k*PB + b] = start of bucket k's run in region b.
// Payload: {src | dst_low6 << 16, val}.
// ---------------------------------------------------------------------------
__global__ __launch_bounds__(512) void build_and_gemm(const int* __restrict__ src,
                                                      const int* __restrict__ dst,
                                                      const float* __restrict__ val,
                                                      const float* __restrict__ X,
                                                      const float* __restrict__ W,
                                                      int* __restrict__ BTt,
                                                      int2* __restrict__ binned,
                                                      float* __restrict__ Y) {
    __shared__ __align__(16) char smem[K1_LDS];
    const int tid = threadIdx.x;

    if (blockIdx.x < PB) {
        // ---------------- partition path ----------------
        int*  cnt    = (int*)smem;
        int*  lcur   = (int*)(smem + 3200);
        int*  wpre   = (int*)(smem + 6400);
        int2* staged = (int2*)(smem + 8448);
        const int b = blockIdx.x, e0 = b * EPB;
        const int lane = tid & 63, w = tid >> 6;      // 8 waves

        for (int k = tid; k < NBKT; k += 512) cnt[k] = 0;
        __syncthreads();

        // single global read: hold edges in registers, count buckets
        int pk[EPT], ps[EPT]; float pv[EPT];
#pragma unroll
        for (int q = 0; q < EPT; ++q) {
            const int i = tid + q * 512;
            if (i < EPB) {
                const int e = e0 + i;
                const int d = dst[e];
                pk[q] = d >> BSHIFT;
                ps[q] = src[e] | ((d & (NPB - 1)) << 16);
                pv[q] = val[e];
                atomicAdd(&cnt[pk[q]], 1);
            } else pk[q] = -1;
        }
        __syncthreads();

        // exclusive scan over 782 buckets: 2 buckets/thread + shfl wave-scan
        const int k0 = 2 * tid, k1 = 2 * tid + 1;
        const int a  = (k0 < NBKT) ? cnt[k0] : 0;
        const int bb = (k1 < NBKT) ? cnt[k1] : 0;
        const int s  = a + bb;
        int x = s;
#pragma unroll
        for (int d = 1; d < 64; d <<= 1) {
            const int y = __shfl_up(x, d, 64);
            if (lane >= d) x += y;
        }
        if (lane == 63) wpre[w] = x;
        __syncthreads();
        int add = 0;
        for (int i = 0; i < w; ++i) add += wpre[i];
        const int excl = add + x - s;
        if (k0 < NBKT) { lcur[k0] = excl;     BTt[k0 * PB + b] = excl; }
        if (k1 < NBKT) { lcur[k1] = excl + a; BTt[k1 * PB + b] = excl + a; }
        if (tid == 0)  BTt[NBKT * PB + b] = EPB;
        __syncthreads();

        // scatter from registers into LDS, bucket-grouped
#pragma unroll
        for (int q = 0; q < EPT; ++q) {
            if (pk[q] >= 0) {
                const int pos = atomicAdd(&lcur[pk[q]], 1);
                staged[pos] = make_int2(ps[q], __float_as_int(pv[q]));
            }
        }
        __syncthreads();

        // linear coalesced copy-out
        for (int i = tid; i < EPB; i += 512)
            binned[e0 + i] = staged[i];
    } else {
        // ---------------- gemm path: 64 rows, thread = (row, float2-col) ----
        float* sX = (float*)smem;
        float* sW = (float*)(smem + 25600);
        const int b2   = blockIdx.x - PB;
        const int row0 = b2 * 64;
        const int nrows = min(64, N_NODES - row0);

        const float4* W4 = (const float4*)W;
        float4* sW4 = (float4*)sW;
        for (int i = tid; i < (IN_DIM * HIDDEN) / 4; i += 512) sW4[i] = W4[i];
        const float4* X4 = (const float4*)(X + (size_t)row0 * IN_DIM);
        float4* sX4 = (float4*)sX;
        const int nf4 = nrows * (IN_DIM / 4);
        for (int i = tid; i < nf4; i += 512) sX4[i] = X4[i];
        __syncthreads();

        const int r = tid >> 3, hh = tid & 7;
        if (r >= nrows) return;
        float2 acc = make_float2(0.f, 0.f);
        const float* xr = &sX[r * IN_DIM];
#pragma unroll
        for (int kk = 0; kk < IN_DIM; ++kk) {
            const float xk = xr[kk];
            const float2 wv = *(const float2*)&sW[kk * HIDDEN + hh * 2];
            acc.x = fmaf(xk, wv.x, acc.x);
            acc.y = fmaf(xk, wv.y, acc.y);
        }
        *(float2*)&Y[(size_t)(row0 + r) * HIDDEN + hh * 2] = acc;
    }
}

// ---------------------------------------------------------------------------
// K2'/K3': sort-free per-bucket SpMM via NATIVE int LDS atomics (ds_add_u32)
// on a fixed-point accumulator. 16-lane groups walk the bucket's runs straight
// from binned (8B broadcast edge + 64B coalesced X row). 2 barriers total.
//  IS_OUT=false: outp = z1 = relu(acc * INV1)          (float2 coalesced)
//  IS_OUT=true : outp = log_softmax((acc*INV2) @ W2)   (8 lanes/node head)
// ---------------------------------------------------------------------------
template <bool IS_OUT>
__global__ __launch_bounds__(512) void spmm_acc(const int* __restrict__ BTt,
                                                const int2* __restrict__ binned,
                                                const float* __restrict__ X,
                                                const float* __restrict__ W2,
                                                float* __restrict__ outp) {
    __shared__ int   acc[NPB * HIDDEN];       // 4 KB int accumulator
    __shared__ int   rsL[PB], reL[PB];        // 2 KB run bounds (coalesced stage)
    __shared__ float sW2[HIDDEN * N_CLASSES]; // 2.56 KB (IS_OUT only)
    const int tid = threadIdx.x, k = blockIdx.x;

    for (int i = tid; i < NPB * HIDDEN; i += 512) acc[i] = 0;
    if (tid < PB) rsL[tid] = BTt[k * PB + tid];
    else          reL[tid - PB] = BTt[(k + 1) * PB + (tid - PB)];
    if (IS_OUT)
        for (int i = tid; i < HIDDEN * N_CLASSES; i += 512) sW2[i] = W2[i];
    __syncthreads();

    // accumulate: 32 groups of 16 lanes; group g owns regions g, g+32, ...
    const float scale = IS_OUT ? SCALE2 : SCALE1;
    const int g = tid >> 4, j = tid & 15;
    for (int t = g; t < PB; t += 32) {
        const int re = reL[t];
        const int2* rb = binned + (size_t)t * EPB;
        for (int p = rsL[t]; p < re; ++p) {
            const int2 e = rb[p];                                  // 8B broadcast
            const float x = X[(size_t)(e.x & 0xFFFF) * HIDDEN + j];// 64B/edge coalesced
            const int qv = __float2int_rn(__int_as_float(e.y) * x * scale);
            atomicAdd(&acc[((e.x >> 16) & (NPB - 1)) * HIDDEN + j], qv);
        }
    }
    __syncthreads();

    if (!IS_OUT) {
        // z1 = relu(acc * INV1): 512 threads x float2 (coalesced)
        const int node = k * NPB + (tid >> 3);
        if (node >= N_NODES) return;
        const int h2 = tid & 7;
        float2 o;
        o.x = fmaxf((float)acc[(tid >> 3) * HIDDEN + h2 * 2 + 0] * INV1, 0.f);
        o.y = fmaxf((float)acc[(tid >> 3) * HIDDEN + h2 * 2 + 1] * INV1, 0.f);
        ((float2*)outp)[(size_t)node * 8 + h2] = o;
    } else {
        // head: 8 lanes/node; lane j5 owns classes [5*j5, 5*j5+5); width-8 shfl
        const int g8 = tid >> 3, j5 = tid & 7;
        const int node = k * NPB + g8;
        if (node >= N_NODES) return;

        float z[HIDDEN];
#pragma unroll
        for (int kk = 0; kk < HIDDEN; ++kk)
            z[kk] = (float)acc[g8 * HIDDEN + kk] * INV2;

        float o[5];
#pragma unroll
        for (int i = 0; i < 5; ++i) o[i] = 0.f;
#pragma unroll
        for (int kk = 0; kk < HIDDEN; ++kk) {
            const float zk = z[kk];
            const float* wr = &sW2[kk * N_CLASSES + j5 * 5];
#pragma unroll
            for (int i = 0; i < 5; ++i) o[i] = fmaf(zk, wr[i], o[i]);
        }

        float m = o[0];
#pragma unroll
        for (int i = 1; i < 5; ++i) m = fmaxf(m, o[i]);
#pragma unroll
        for (int d = 1; d < 8; d <<= 1) m = fmaxf(m, __shfl_xor(m, d, 8));
        float se = 0.f;
#pragma unroll
        for (int i = 0; i < 5; ++i) se += __expf(o[i] - m);
#pragma unroll
        for (int d = 1; d < 8; d <<= 1) se += __shfl_xor(se, d, 8);
        const float lse = m + __logf(se);

        float* orow = outp + (size_t)node * N_CLASSES + j5 * 5;
#pragma unroll
        for (int i = 0; i < 5; ++i) orow[i] = o[i] - lse;
    }
}

extern "C" void kernel_launch(void* const* d_in, const int* in_sizes, int n_in,
                              void* d_out, int out_size, void* d_ws, size_t ws_size,
                              hipStream_t stream) {
    const float* features = (const float*)d_in[0];  // [50000,100]
    const int*   edge_src = (const int*)d_in[1];    // [800000]
    const int*   edge_dst = (const int*)d_in[2];    // [800000]
    const float* edge_val = (const float*)d_in[3];  // [800000]
    const float* W1       = (const float*)d_in[4];  // [100,16]
    const float* W2       = (const float*)d_in[5];  // [16,40]
    float*       out      = (float*)d_out;          // [50000,40]

    char* base = (char*)d_ws;
    const size_t HNB = (size_t)N_NODES * HIDDEN * sizeof(float);     // 3.2 MB
    float* y1     = (float*)(base);
    float* z1     = (float*)(base + HNB);
    int2*  binned = (int2*) (base + 2 * HNB);                        // 6.4 MB
    int*   BTt    = (int*)  (base + 2 * HNB + (size_t)N_EDGES * 8);  // ~802 KB

    // K1: partition (blocks 0..255) || gemm y1 = X@W1 (blocks 256..1037)
    build_and_gemm<<<PB + GEMMB, 512, 0, stream>>>(edge_src, edge_dst, edge_val,
                                                   features, W1, BTt, binned, y1);
    // K2': z1 = relu(A @ y1), sort-free int-atomic accumulate
    spmm_acc<false><<<NBKT, 512, 0, stream>>>(BTt, binned, y1, nullptr, z1);
    // K3': out = log_softmax((A @ z1) @ W2), accumulate + head in one block
    spmm_acc<true><<<NBKT, 512, 0, stream>>>(BTt, binned, z1, W2, out);
}

// Round 13
// 125.727 us; speedup vs baseline: 1.3475x; 1.3475x over previous
//
#include <hip/hip_runtime.h>

#define N_NODES   50000
#define N_EDGES   800000
#define IN_DIM    100
#define HIDDEN    16
#define N_CLASSES 40

// Bucketing geometry: bucket = dst >> 6 (64 nodes per bucket)
#define BSHIFT 6
#define NPB    64                        // nodes per bucket
#define NBKT   782                       // ceil(N_NODES / NPB)
#define PB     256                       // partition blocks
#define EPB    3125                      // edges per partition block (256*3125 = 800000)
#define EPT    7                         // max edges held in regs per thread (ceil(3125/512))
#define CAP    2048                      // per-bucket edge capacity (mean 1024, sd 32)
#define GEMMB  782                       // gemm sub-grid: ceil(50000/64)
#define GNODES 32                        // nodes per gather_out block (8 lanes/node)

// K1 LDS union:
//  partition: cnt[782 -> pad 800 ints]@0 | lcur[800 ints]@3200 | wpre[8]@6400
//             | staged int2[3125]@8448 .. 33448
//  gemm:      sX[64*100]@0 .. 25600 | sW[1600]@25600 .. 32000
#define K1_LDS 33456

// ---------------------------------------------------------------------------
// K1: blocks [0,PB) partition the edge list (edges held in REGISTERS between
// count and scatter -> single global read); blocks [PB, PB+GEMMB) compute
// y1 = X @ W1 concurrently. Scan is 2-barrier shfl wave-scan.
// BTt transposed: BTt[k*PB + b] = start of bucket k's run in block b's region.
// Payload: {src | dst_low6 << 16, val}.
// ---------------------------------------------------------------------------
__global__ __launch_bounds__(512) void build_and_gemm(const int* __restrict__ src,
                                                      const int* __restrict__ dst,
                                                      const float* __restrict__ val,
                                                      const float* __restrict__ X,
                                                      const float* __restrict__ W,
                                                      int* __restrict__ BTt,
                                                      int2* __restrict__ binned,
                                                      float* __restrict__ Y) {
    __shared__ __align__(16) char smem[K1_LDS];
    const int tid = threadIdx.x;

    if (blockIdx.x < PB) {
        // ---------------- partition path ----------------
        int*  cnt    = (int*)smem;
        int*  lcur   = (int*)(smem + 3200);
        int*  wpre   = (int*)(smem + 6400);
        int2* staged = (int2*)(smem + 8448);
        const int b = blockIdx.x, e0 = b * EPB;
        const int lane = tid & 63, w = tid >> 6;      // 8 waves

        for (int k = tid; k < NBKT; k += 512) cnt[k] = 0;
        __syncthreads();

        // single global read: hold edges in registers, count buckets
        int pk[EPT], ps[EPT]; float pv[EPT];
#pragma unroll
        for (int q = 0; q < EPT; ++q) {
            const int i = tid + q * 512;
            if (i < EPB) {
                const int e = e0 + i;
                const int d = dst[e];
                pk[q] = d >> BSHIFT;
                ps[q] = src[e] | ((d & (NPB - 1)) << 16);
                pv[q] = val[e];
                atomicAdd(&cnt[pk[q]], 1);
            } else pk[q] = -1;
        }
        __syncthreads();

        // 2-barrier exclusive scan over 782 buckets (2 buckets per thread)
        const int k0 = 2 * tid, k1 = 2 * tid + 1;
        const int a  = (k0 < NBKT) ? cnt[k0] : 0;
        const int bb = (k1 < NBKT) ? cnt[k1] : 0;
        const int s  = a + bb;
        int x = s;
#pragma unroll
        for (int d = 1; d < 64; d <<= 1) {
            const int y = __shfl_up(x, d, 64);
            if (lane >= d) x += y;
        }
        if (lane == 63) wpre[w] = x;
        __syncthreads();
        int add = 0;
        for (int i = 0; i < w; ++i) add += wpre[i];
        const int excl = add + x - s;
        if (k0 < NBKT) { lcur[k0] = excl;     BTt[k0 * PB + b] = excl; }
        if (k1 < NBKT) { lcur[k1] = excl + a; BTt[k1 * PB + b] = excl + a; }
        if (tid == 0)  BTt[NBKT * PB + b] = EPB;
        __syncthreads();

        // scatter from registers into LDS, bucket-grouped
#pragma unroll
        for (int q = 0; q < EPT; ++q) {
            if (pk[q] >= 0) {
                const int pos = atomicAdd(&lcur[pk[q]], 1);
                staged[pos] = make_int2(ps[q], __float_as_int(pv[q]));
            }
        }
        __syncthreads();

        // linear coalesced copy-out
        for (int i = tid; i < EPB; i += 512)
            binned[e0 + i] = staged[i];
    } else {
        // ---------------- gemm path: 64 rows, thread = (row, float2-col) ----
        float* sX = (float*)smem;
        float* sW = (float*)(smem + 25600);
        const int b2   = blockIdx.x - PB;
        const int row0 = b2 * 64;
        const int nrows = min(64, N_NODES - row0);

        const float4* W4 = (const float4*)W;
        float4* sW4 = (float4*)sW;
        for (int i = tid; i < (IN_DIM * HIDDEN) / 4; i += 512) sW4[i] = W4[i];
        const float4* X4 = (const float4*)(X + (size_t)row0 * IN_DIM);
        float4* sX4 = (float4*)sX;
        const int nf4 = nrows * (IN_DIM / 4);
        for (int i = tid; i < nf4; i += 512) sX4[i] = X4[i];
        __syncthreads();

        const int r = tid >> 3, hh = tid & 7;
        if (r >= nrows) return;
        float2 acc = make_float2(0.f, 0.f);
        const float* xr = &sX[r * IN_DIM];
#pragma unroll
        for (int k = 0; k < IN_DIM; ++k) {
            const float xk = xr[k];
            const float2 wv = *(const float2*)&sW[k * HIDDEN + hh * 2];
            acc.x = fmaf(xk, wv.x, acc.x);
            acc.y = fmaf(xk, wv.y, acc.y);
        }
        *(float2*)&Y[(size_t)(row0 + r) * HIDDEN + hh * 2] = acc;
    }
}

// ---------------------------------------------------------------------------
// K2: per-bucket sort ENTIRELY in LDS (single global read of binned) +
// write sorted/meta for K3 + fused gather1: z1 = relu(A @ y1), 4 lanes/node.
// ---------------------------------------------------------------------------
__global__ __launch_bounds__(256) void sort_gather(const int* __restrict__ BTt,
                                                   const int2* __restrict__ binned,
                                                   const float* __restrict__ Xin,
                                                   int2* __restrict__ sorted,
                                                   int2* __restrict__ meta,
                                                   float* __restrict__ Z) {
    __shared__ int2 raw[CAP];          // 16 KB: bucket edges in arrival order
    __shared__ int2 srt[CAP];          // 16 KB: node-sorted
    __shared__ int  cnt[NPB];
    __shared__ int  cur[NPB];
    __shared__ int  wsum[4];
    const int tid = threadIdx.x, k = blockIdx.x;
    const int lane = tid & 63, w = tid >> 6;

    if (tid < NPB) cnt[tid] = 0;

    // coalesced run boundaries; block-scan of 256 run lengths -> LDS offsets
    const int rs = BTt[k * PB + tid];
    const int re = BTt[(k + 1) * PB + tid];
    const int len = re - rs;
    int x = len;
#pragma unroll
    for (int d = 1; d < 64; d <<= 1) {
        const int y = __shfl_up(x, d, 64);
        if (lane >= d) x += y;
    }
    if (lane == 63) wsum[w] = x;
    __syncthreads();
    int add = 0;
    for (int i = 0; i < w; ++i) add += wsum[i];
    const int tot = wsum[0] + wsum[1] + wsum[2] + wsum[3];

    // single global read: stage this bucket's runs into LDS
    int o = add + x - len;
    const int2* rb = binned + (size_t)tid * EPB;
    for (int p = rs; p < re; ++p, ++o) raw[o] = rb[p];
    __syncthreads();

    // node histogram (LDS only)
    for (int i = tid; i < tot; i += 256)
        atomicAdd(&cnt[(raw[i].x >> 16) & (NPB - 1)], 1);
    __syncthreads();

    // wave scan with even-pad (16B-aligned segments for K3's int4 loads)
    if (tid < NPB) {
        const int v  = cnt[tid];
        const int vp = (v + 1) & ~1;
        int xx = vp;
#pragma unroll
        for (int d = 1; d < 64; d <<= 1) {
            const int y = __shfl_up(xx, d, 64);
            if (tid >= d) xx += y;
        }
        const int excl = xx - vp;
        cur[tid] = excl;
        const int node = k * NPB + tid;
        if (node < N_NODES) meta[node] = make_int2(k * CAP + excl, v);
        if (tid == NPB - 1) wsum[0] = xx;     // padded total (wsum free now)
    }
    __syncthreads();
    const int padTot = wsum[0];

    // rank-scatter LDS -> LDS
    for (int i = tid; i < tot; i += 256) {
        const int2 e = raw[i];
        const int pos = atomicAdd(&cur[(e.x >> 16) & (NPB - 1)], 1);
        srt[pos] = make_int2(e.x & 0xFFFF, e.y);
    }
    __syncthreads();

    // coalesced copy-out for K3
    for (int i = tid; i < padTot; i += 256)
        sorted[(size_t)k * CAP + i] = srt[i];

    // fused gather1: 4 lanes per node, float4 of the 16-wide row
    const int g = tid >> 2, q = tid & 3;
    const int node = k * NPB + g;
    if (node >= N_NODES) return;
    const int deg = cnt[g];
    const int beg = cur[g] - deg;      // cur[g] == excl + deg after ranking
    const float4* X4 = (const float4*)Xin;
    float4 acc = make_float4(0.f, 0.f, 0.f, 0.f);
    for (int p = beg; p < beg + deg; ++p) {
        const int2 e = srt[p];
        const float v = __int_as_float(e.y);
        const float4 xv = X4[(size_t)e.x * 4 + q];
        acc.x = fmaf(v, xv.x, acc.x);
        acc.y = fmaf(v, xv.y, acc.y);
        acc.z = fmaf(v, xv.z, acc.z);
        acc.w = fmaf(v, xv.w, acc.w);
    }
    acc.x = fmaxf(acc.x, 0.f); acc.y = fmaxf(acc.y, 0.f);
    acc.z = fmaxf(acc.z, 0.f); acc.w = fmaxf(acc.w, 0.f);
    ((float4*)Z)[(size_t)node * 4 + q] = acc;
}

// ---------------------------------------------------------------------------
// K3: z2 = A @ z1 (8-lane register gather) -> padded LDS transpose ->
// out = log_softmax(z2 @ W2). Lane j owns classes [5j, 5j+5); width-8 shfl.
// ---------------------------------------------------------------------------
__global__ __launch_bounds__(256) void gather_out(const int2* __restrict__ meta,
                                                  const int2* __restrict__ sorted,
                                                  const float* __restrict__ X,
                                                  const float* __restrict__ W2,
                                                  float* __restrict__ out) {
    __shared__ float sW[HIDDEN * N_CLASSES];   // 2.56 KB
    __shared__ float zt[GNODES * 17];          // +1 pad: conflict-free transpose
    const int tid = threadIdx.x;
    for (int i = tid; i < HIDDEN * N_CLASSES; i += 256) sW[i] = W2[i];

    const int g = tid >> 3, j = tid & 7;
    const int n = blockIdx.x * GNODES + g;

    float2 acc = make_float2(0.f, 0.f);
    if (n < N_NODES) {
        const int2 md = meta[n];
        const int beg = md.x, end = md.x + md.y;
        const float2* X2 = (const float2*)X;
        int p = beg;
        for (; p + 4 <= end; p += 4) {
            const int4 ea = *(const int4*)&sorted[p];
            const int4 eb = *(const int4*)&sorted[p + 2];
            const float2 x0 = X2[(size_t)ea.x * 8 + j];
            const float2 x1 = X2[(size_t)ea.z * 8 + j];
            const float2 x2 = X2[(size_t)eb.x * 8 + j];
            const float2 x3 = X2[(size_t)eb.z * 8 + j];
            const float v0 = __int_as_float(ea.y), v1 = __int_as_float(ea.w);
            const float v2 = __int_as_float(eb.y), v3 = __int_as_float(eb.w);
            acc.x = fmaf(v0, x0.x, acc.x); acc.y = fmaf(v0, x0.y, acc.y);
            acc.x = fmaf(v1, x1.x, acc.x); acc.y = fmaf(v1, x1.y, acc.y);
            acc.x = fmaf(v2, x2.x, acc.x); acc.y = fmaf(v2, x2.y, acc.y);
            acc.x = fmaf(v3, x3.x, acc.x); acc.y = fmaf(v3, x3.y, acc.y);
        }
        for (; p < end; ++p) {
            const int2 e = sorted[p];
            const float2 xv = X2[(size_t)e.x * 8 + j];
            const float v = __int_as_float(e.y);
            acc.x = fmaf(v, xv.x, acc.x); acc.y = fmaf(v, xv.y, acc.y);
        }
    }
    zt[g * 17 + j * 2]     = acc.x;
    zt[g * 17 + j * 2 + 1] = acc.y;
    __syncthreads();
    if (n >= N_NODES) return;

    float z[HIDDEN];
#pragma unroll
    for (int k = 0; k < HIDDEN; ++k) z[k] = zt[g * 17 + k];

    float o[5];
#pragma unroll
    for (int i = 0; i < 5; ++i) o[i] = 0.f;
#pragma unroll
    for (int k = 0; k < HIDDEN; ++k) {
        const float zk = z[k];
#pragma unroll
        for (int i = 0; i < 5; ++i)
            o[i] = fmaf(zk, sW[k * N_CLASSES + j * 5 + i], o[i]);
    }

    float m = o[0];
#pragma unroll
    for (int i = 1; i < 5; ++i) m = fmaxf(m, o[i]);
#pragma unroll
    for (int d = 1; d < 8; d <<= 1) m = fmaxf(m, __shfl_xor(m, d, 8));
    float se = 0.f;
#pragma unroll
    for (int i = 0; i < 5; ++i) se += __expf(o[i] - m);
#pragma unroll
    for (int d = 1; d < 8; d <<= 1) se += __shfl_xor(se, d, 8);
    const float lse = m + __logf(se);

    float* orow = out + (size_t)n * N_CLASSES + j * 5;
#pragma unroll
    for (int i = 0; i < 5; ++i) orow[i] = o[i] - lse;
}

extern "C" void kernel_launch(void* const* d_in, const int* in_sizes, int n_in,
                              void* d_out, int out_size, void* d_ws, size_t ws_size,
                              hipStream_t stream) {
    const float* features = (const float*)d_in[0];  // [50000,100]
    const int*   edge_src = (const int*)d_in[1];    // [800000]
    const int*   edge_dst = (const int*)d_in[2];    // [800000]
    const float* edge_val = (const float*)d_in[3];  // [800000]
    const float* W1       = (const float*)d_in[4];  // [100,16]
    const float* W2       = (const float*)d_in[5];  // [16,40]
    float*       out      = (float*)d_out;          // [50000,40]

    char* base = (char*)d_ws;
    const size_t HNB = (size_t)N_NODES * HIDDEN * sizeof(float);       // 3.2 MB
    float* y1     = (float*)(base);
    float* z1     = (float*)(base + HNB);
    int2*  binned = (int2*) (base + 2 * HNB);                          // 6.4 MB
    int2*  sortd  = (int2*) (base + 2 * HNB + (size_t)N_EDGES * 8);    // 12.8 MB
    char*  tail   = base + 2 * HNB + (size_t)N_EDGES * 8
                         + (size_t)NBKT * CAP * 8;
    int*   BTt    = (int*) (tail);                                     // 783*256*4 ≈ 802 KB
    int2*  meta   = (int2*)(tail + (((size_t)(NBKT + 1) * PB * 4 + 255) & ~255ULL));

    // K1: partition (blocks 0..255) || gemm y1 = X@W1 (blocks 256..1037)
    build_and_gemm<<<PB + GEMMB, 512, 0, stream>>>(edge_src, edge_dst, edge_val,
                                                   features, W1, BTt, binned, y1);
    // K2: per-bucket LDS sort -> sorted/meta + fused z1 = relu(A @ y1)
    sort_gather<<<NBKT, 256, 0, stream>>>(BTt, binned, y1, sortd, meta, z1);
    // K3: z2 = A @ z1 fused with log_softmax(z2 @ W2)
    gather_out<<<(N_NODES + GNODES - 1) / GNODES, 256, 0, stream>>>(meta, sortd, z1, W2, out);
}